// Round 10
// baseline (183.254 us; speedup 1.0000x reference)
//
#include <hip/hip_runtime.h>
#include <hip/hip_bf16.h>
#include <math.h>

// out[b] = max_o( 2 * gelu_tanh( x[b,:] . weight[o,:] + bias[o] ) )
// 4096 x 4096 x 4096, fp32 in, fp32 out[4096].
//
// Round 10: cross-block anti-phase overlap. 2 blocks/CU (grid 512), each
// 4 waves / 256x128 tile / BK=32 / 48 KiB dbuf LDS. Intra-block schedule is
// deliberately simple (read->MFMA->bar->stage->vmcnt(6)->bar); the LDS|MFMA
// overlap comes from the two independent blocks on each CU drifting into
// anti-phase (m114 mechanism) instead of hand-built phase pipelines, which
// rounds 5-9 showed cannot beat ~45% MfmaUtil under 1-block barrier
// lockstep. T1 XCD region swizzle (8x8 tiles, all 64 blocks of an XCD
// co-resident), T2 XOR swizzle (chunk ^ row&3, 2-way = free), T5 setprio.

typedef unsigned short u16;
typedef short bf16x8 __attribute__((ext_vector_type(8)));   // 8 bf16 = 4 VGPRs
typedef float f32x4 __attribute__((ext_vector_type(4)));
typedef unsigned short ushort8 __attribute__((ext_vector_type(8)));

#define MDIM 4096
#define NDIM 4096
#define KD   4096
#define BM 256
#define BN 128
#define BK 32
#define NKT (KD / BK)          // 128 K-tiles
#define NTN (NDIM / BN)        // 32 column tiles
#define ABUF 8192              // u16 per A buffer (256x32)
#define BBUF 4096              // u16 per B buffer (128x32)
#define BUFSZ (ABUF + BBUF)    // 12288 u16 = 24 KiB

__device__ __forceinline__ u16 f2bf(float f) {
  unsigned int u = __float_as_uint(f);
  u += 0x7fffu + ((u >> 16) & 1u);
  return (u16)(u >> 16);
}

// both converts in one launch
__global__ void f32_to_bf16_kernel(const float* __restrict__ in0,
                                   const float* __restrict__ in1,
                                   u16* __restrict__ out0,
                                   u16* __restrict__ out1, int n8) {
  int i = blockIdx.x * blockDim.x + threadIdx.x;
  int stride = gridDim.x * blockDim.x;
  for (; i < 2 * n8; i += stride) {
    const float* in = (i < n8) ? in0 : in1;
    u16* out = (i < n8) ? out0 : out1;
    int k = (i < n8) ? i : i - n8;
    const float4* p = (const float4*)in + (size_t)k * 2;
    float4 a = p[0];
    float4 b = p[1];
    ushort8 o;
    o[0] = f2bf(a.x); o[1] = f2bf(a.y); o[2] = f2bf(a.z); o[3] = f2bf(a.w);
    o[4] = f2bf(b.x); o[5] = f2bf(b.y); o[6] = f2bf(b.z); o[7] = f2bf(b.w);
    ((ushort8*)out)[k] = o;
  }
}

__device__ __forceinline__ void gload_lds16(const u16* g, u16* l) {
  __builtin_amdgcn_global_load_lds(
      (__attribute__((address_space(1))) void*)(g),
      (__attribute__((address_space(3))) void*)(l), 16, 0, 0);
}

// Stage one K32 tile into buffer c: A = 4 gloads, B = 2 gloads per thread.
// LDS dest linear; global src pre-swizzled (chunk ^ (row&3)), rule #21.
#define STAGE(c)                                                          \
  {                                                                       \
    _Pragma("unroll")                                                     \
    for (int q = 0; q < 4; ++q) {                                         \
      gload_lds16(gpA[q], sm + (c) * BUFSZ + q * 2048 + wdof);            \
      gpA[q] += BK;                                                       \
    }                                                                     \
    _Pragma("unroll")                                                     \
    for (int q = 0; q < 2; ++q) {                                         \
      gload_lds16(gpB[q], sm + (c) * BUFSZ + ABUF + q * 2048 + wdof);     \
      gpB[q] += BK;                                                       \
    }                                                                     \
  }

// Read 12 frags from buffer c and run the 32-MFMA K32 step.
#define COMPUTE(c)                                                        \
  {                                                                       \
    bf16x8 af[8], bf[4];                                                  \
    _Pragma("unroll")                                                     \
    for (int m = 0; m < 8; ++m)                                           \
      af[m] = *(const bf16x8*)(ARB[(c)] + m * 512);                       \
    _Pragma("unroll")                                                     \
    for (int n = 0; n < 4; ++n)                                           \
      bf[n] = *(const bf16x8*)(BRB[(c)] + n * 512);                       \
    __builtin_amdgcn_s_setprio(1);                                        \
    _Pragma("unroll")                                                     \
    for (int m = 0; m < 8; ++m)                                           \
      _Pragma("unroll")                                                   \
      for (int n = 0; n < 4; ++n)                                         \
        acc[m][n] = __builtin_amdgcn_mfma_f32_16x16x32_bf16(              \
            af[m], bf[n], acc[m][n], 0, 0, 0);                            \
    __builtin_amdgcn_s_setprio(0);                                        \
  }

#define VM6 asm volatile("s_waitcnt vmcnt(6)" ::: "memory");
#define VM0 asm volatile("s_waitcnt vmcnt(0)" ::: "memory");
#define VMNONE

// One K32 step on buffer c:
//   compute(c); barrier (all waves done reading c);
//   [stage tile kt+2 -> c]; vmcnt (tile kt+1 landed); barrier.
#define TILE(c, ST, VMW)                                                  \
  {                                                                       \
    COMPUTE(c)                                                            \
    __builtin_amdgcn_s_barrier();                                         \
    if (ST) { STAGE(c) }                                                  \
    VMW                                                                   \
    __builtin_amdgcn_s_barrier();                                         \
  }

__global__ __launch_bounds__(256, 2) void gemm_gelu_max_kernel(
    const u16* __restrict__ A,    // x bf16 [4096][4096], K contiguous
    const u16* __restrict__ Bw,   // weight bf16 [4096][4096], K contiguous
    const float* __restrict__ bias,
    float* __restrict__ partials) {
  __shared__ __align__(16) u16 sm[2 * BUFSZ];  // 48 KiB
  __shared__ float pmx[4][128];                // 2 KiB

  const int t = threadIdx.x;
  const int wave = t >> 6;
  const int lane = t & 63;
  const int warp_m = wave >> 1;        // 0..1: A 128-row half
  const int warp_n = wave & 1;         // 0..1: B 64-col half
  const int l15 = lane & 15;
  const int l4 = lane >> 4;            // 16B chunk within 64B row
  const int wdof = wave * 512;         // wave's gload_lds dest slot (u16)

  // T1: XCD region swizzle. grid 512 = 16(ty) x 32(tx); XCD c8 owns an
  // 8x8 tile region (all 64 of its blocks co-resident at 2 blocks/CU).
  const int bid = blockIdx.x;
  const int c8 = bid & 7;
  const int j = bid >> 3;              // 0..63
  const int ty = ((c8 >> 2) << 3) + (j & 7);    // 0..15
  const int tx = ((c8 & 3) << 3) + (j >> 3);    // 0..31
  const int brow = ty * BM;
  const int bcol = tx * BN;

  // T2 swizzled per-lane read offset: chunk' = l4 ^ (l15&3)  (u16 elems)
  const int cko = ((l4 ^ (l15 & 3)) << 3);

  // LDS read base pointers per buffer; frag offsets are const immediates
  const u16* ARB[2];
  const u16* BRB[2];
#pragma unroll
  for (int c = 0; c < 2; ++c) {
    ARB[c] = sm + c * BUFSZ + (warp_m * 128 + l15) * 32 + cko;
    BRB[c] = sm + c * BUFSZ + ABUF + (warp_n * 64 + l15) * 32 + cko;
  }

  // running global staging pointers (pre-swizzled source, rule #21)
  const u16* gpA[4];
  const u16* gpB[2];
#pragma unroll
  for (int q = 0; q < 4; ++q) {
    const int ch = q * 256 + t;        // 0..1023 A chunks
    const int r = ch >> 2;
    const int sw = ((ch & 3) ^ (r & 3)) << 3;
    gpA[q] = A + (size_t)(brow + r) * KD + sw;
  }
#pragma unroll
  for (int q = 0; q < 2; ++q) {
    const int ch = q * 256 + t;        // 0..511 B chunks
    const int r = ch >> 2;
    const int sw = ((ch & 3) ^ (r & 3)) << 3;
    gpB[q] = Bw + (size_t)(bcol + r) * KD + sw;
  }

  f32x4 acc[8][4] = {};   // per-wave 128x64 output

  // prologue: tile0 -> buf0, tile1 -> buf1
  STAGE(0)
  STAGE(1)
  asm volatile("s_waitcnt vmcnt(6)" ::: "memory");
  __builtin_amdgcn_s_barrier();

  for (int kt2 = 0; kt2 < NKT / 2 - 1; ++kt2) {   // kt = 0..125
    TILE(0, 1, VM6)
    TILE(1, 1, VM6)
  }
  TILE(0, 0, VM0)      // kt = 126 (tile 127 already staged; drain)
  TILE(1, 0, VMNONE)   // kt = 127

  // ---- epilogue: bias + 2*gelu_tanh, row-max over cols
  // C/D layout per 16x16 frag: col = l15, row = l4*4 + j
  float rmax_[8][4];
#pragma unroll
  for (int m = 0; m < 8; ++m)
#pragma unroll
    for (int j2 = 0; j2 < 4; ++j2) rmax_[m][j2] = -1e30f;

#pragma unroll
  for (int n = 0; n < 4; ++n) {
    const float bv = bias[bcol + warp_n * 64 + n * 16 + l15];
#pragma unroll
    for (int m = 0; m < 8; ++m) {
#pragma unroll
      for (int j2 = 0; j2 < 4; ++j2) {
        float x = acc[m][n][j2] + bv;
        float u = 0.7978845608f * x * (1.0f + 0.044715f * x * x);
        float e = exp2f(u * 2.8853900817779268f);   // 2*log2(e)
        float r = __builtin_amdgcn_rcpf(e + 1.0f);
        float g = 2.0f * x * (1.0f - r);
        rmax_[m][j2] = fmaxf(rmax_[m][j2], g);
      }
    }
  }

#pragma unroll
  for (int m = 0; m < 8; ++m) {
#pragma unroll
    for (int j2 = 0; j2 < 4; ++j2) {
      float v = rmax_[m][j2];
      v = fmaxf(v, __shfl_xor(v, 1, 64));
      v = fmaxf(v, __shfl_xor(v, 2, 64));
      v = fmaxf(v, __shfl_xor(v, 4, 64));
      v = fmaxf(v, __shfl_xor(v, 8, 64));
      if (l15 == 0) pmx[wave][m * 16 + l4 * 4 + j2] = v;
    }
  }
  __syncthreads();

  if (t < 256) {
    int gm = t >> 7;               // which 128-row half
    int r = t & 127;
    float v = fmaxf(pmx[gm * 2 + 0][r], pmx[gm * 2 + 1][r]);
    partials[(size_t)tx * MDIM + brow + t] = v;
  }
}

__global__ void rowmax_kernel(const float* __restrict__ partials,
                              float* __restrict__ out) {
  int r = blockIdx.x * blockDim.x + threadIdx.x;
  if (r < MDIM) {
    float m = -1e30f;
#pragma unroll
    for (int tt = 0; tt < NTN; ++tt) m = fmaxf(m, partials[(size_t)tt * MDIM + r]);
    out[r] = m;
  }
}

extern "C" void kernel_launch(void* const* d_in, const int* in_sizes, int n_in,
                              void* d_out, int out_size, void* d_ws, size_t ws_size,
                              hipStream_t stream) {
  const float* x = (const float*)d_in[0];
  const float* w = (const float*)d_in[1];
  const float* bias = (const float*)d_in[2];
  float* out = (float*)d_out;

  u16* xb = (u16*)d_ws;
  u16* wb = xb + (size_t)MDIM * KD;
  float* partials = (float*)(wb + (size_t)NDIM * KD);

  const int n8 = (MDIM * KD) / 8;
  f32_to_bf16_kernel<<<2048, 256, 0, stream>>>(x, w, xb, wb, n8);

  gemm_gelu_max_kernel<<<dim3(512), 256, 0, stream>>>(xb, wb, bias, partials);

  rowmax_kernel<<<MDIM / 256, 256, 0, stream>>>(partials, out);
}